// Round 7
// baseline (61.271 us; speedup 1.0000x reference)
//
#include <hip/hip_runtime.h>
#include <math.h>

#define OUT_H 152
#define OUT_W 272
#define HW 41344
#define NOBJ 64
#define NB 8
#define NID 537
#define EMB 256

#define NFBLK 162                 /* focal blocks per batch: ceil(41344/256) */
#define NFOCAL (NFBLK * NB)       /* 1296 */
#define NIDG   128                /* grouped id blocks: (obj i, batch-half) */

/* workspace float offsets — every slot written by kernel A before B reads */
#define OF_FP    0                /* 1296*3 focal partials (pos,neg,np) */
#define OF_IDNLL (NFOCAL * 3)     /* 512 per-object id NLL */

__device__ inline float waveRedSum(float v) {
  for (int off = 32; off; off >>= 1) v += __shfl_down(v, off, 64);
  return v;
}

struct PrepOut {
  float cxf, cyf, radius, inv2s2, vm, v;
  float wh[8];
  int ind, id;
};

__device__ __forceinline__ PrepOut prep_obj(const float* __restrict__ ann1,
                                            const float* __restrict__ ann2,
                                            int b, int i) {
  const float* a1 = ann1 + (b * NOBJ + i) * 8;
  const float* A2 = ann2 + b * NOBJ * 8;

  float cx_raw = a1[0] * (float)OUT_W;
  float cy_raw = a1[1] * (float)OUT_H;
  float w = a1[2] * (float)OUT_W;
  float h = a1[3] * (float)OUT_H;
  float x1 = cx_raw - 0.5f * w, y1 = cy_raw - 0.5f * h;
  float x2 = x1 + w, y2 = y1 + h;
  float cx = fminf(fmaxf(cx_raw, 0.f), (float)(OUT_W - 1));
  float cy = fminf(fmaxf(cy_raw, 0.f), (float)(OUT_H - 1));
  int ctx = (int)cx, cty = (int)cy;

  float hc = ceilf(h), wc = ceilf(w);
  float b1 = hc + wc;
  float c1 = wc * hc * 0.3f / 1.7f;
  float r1 = (b1 + sqrtf(fmaxf(b1 * b1 - 4.f * c1, 0.f))) * 0.5f;
  float b2 = 2.f * (hc + wc);
  float c2 = 0.3f * wc * hc;
  float r2 = (b2 + sqrtf(fmaxf(b2 * b2 - 16.f * c2, 0.f))) * 0.5f;
  float b3 = -1.4f * (hc + wc);
  float c3 = -0.3f * wc * hc;
  float r3 = (b3 + sqrtf(fmaxf(b3 * b3 - 11.2f * c3, 0.f))) * 0.5f;
  float radius = fmaxf(floorf(fminf(fminf(r1, r2), r3)), 0.f);
  float sigma = (2.f * radius + 1.f) / 6.f;

  PrepOut P;
  P.cxf = (float)ctx;
  P.cyf = (float)cty;
  P.radius = radius;
  P.inv2s2 = 1.f / (2.f * sigma * sigma);

  float pid = a1[5];
  int jm = -1;
  for (int j = 0; j < NOBJ; ++j) {
    if (A2[j * 8 + 5] == pid) { jm = j; break; }
  }
  bool has = (jm >= 0);
  const float* t1 = A2 + (has ? jm : 0) * 8;
  float cx2 = t1[0] * (float)OUT_W, cy2 = t1[1] * (float)OUT_H;
  float w2 = t1[2] * (float)OUT_W, h2 = t1[3] * (float)OUT_H;
  float x1t = cx2 - 0.5f * w2, y1t = cy2 - 0.5f * h2;
  float x2t = x1t + w2, y2t = y1t + h2;

  bool valid = has && (h > 0.f) && (w > 0.f) && (h2 > 0.f) && (w2 > 0.f);
  float vm = valid ? 1.f : 0.f;
  P.vm = vm;
  P.v = a1[6] * vm;
  P.wh[0] = (P.cxf - x1) * vm;  P.wh[1] = (x2 - P.cxf) * vm;
  P.wh[2] = (P.cyf - y1) * vm;  P.wh[3] = (y2 - P.cyf) * vm;
  P.wh[4] = (P.cxf - x1t) * vm; P.wh[5] = (x2t - P.cxf) * vm;
  P.wh[6] = (P.cyf - y1t) * vm; P.wh[7] = (y2t - P.cyf) * vm;
  P.ind = valid ? (cty * OUT_W + ctx) : 0;
  P.id = valid ? (int)pid : 0;
  return P;
}

__global__ void __launch_bounds__(256)
main_kernel(const float* __restrict__ cls,
            const float* __restrict__ identis,
            const float* __restrict__ W_id,
            const float* __restrict__ b_id,
            const float* __restrict__ ann1,
            const float* __restrict__ ann2,
            float* __restrict__ F) {
  if (blockIdx.x < NFOCAL) {
    /* ---------- focal branch with object culling ---------- */
    int blk = blockIdx.x;
    int b = blk / NFBLK;
    int bx = blk - b * NFBLK;
    int p0 = bx * 256;
    int p = p0 + threadIdx.x;

    __shared__ unsigned s_pk[64];          /* ctx | cty<<9 | rad<<17 */
    __shared__ float s_inv[64];
    __shared__ unsigned long long s_mask;
    if (threadIdx.x < 64) {                /* exactly wave 0 */
      PrepOut P = prep_obj(ann1, ann2, b, threadIdx.x);
      int ctx = (int)P.cxf, cty = (int)P.cyf, r = (int)P.radius;
      s_pk[threadIdx.x]  = (unsigned)ctx | ((unsigned)cty << 9) | ((unsigned)r << 17);
      s_inv[threadIdx.x] = P.inv2s2;
      int y0 = p0 / OUT_W;
      int y1 = (p0 + 255) / OUT_W;
      bool two_rows = (y1 > y0);
      int x0 = two_rows ? 0 : (p0 - y0 * OUT_W);
      int x1 = two_rows ? (OUT_W - 1) : (p0 + 255 - y0 * OUT_W);
      bool act = (cty + r >= y0) && (cty - r <= y1) &&
                 (ctx + r >= x0) && (ctx - r <= x1);
      unsigned long long m = __ballot(act);
      if (threadIdx.x == 0) s_mask = m;
    }
    __syncthreads();

    float pos_l = 0.f, neg_l = 0.f, npos = 0.f;
    if (p < HW) {
      float xf = (float)(p % OUT_W);
      float yf = (float)(p / OUT_W);
      float gt = 0.f;
      unsigned long long m = s_mask;       /* wave-uniform loop */
      while (m) {
        int o = __ffsll((unsigned long long)m) - 1;
        m &= m - 1;
        unsigned pk = s_pk[o];
        float inv = s_inv[o];
        float cxv = (float)(pk & 511u);
        float cyv = (float)((pk >> 9) & 255u);
        float rv  = (float)(pk >> 17);
        float dy = yf - cyv;
        float dx = xf - cxv;
        if (fabsf(dy) <= rv && fabsf(dx) <= rv) {
          gt = fmaxf(gt, __expf(-(dy * dy + dx * dx) * inv));
        }
      }
      float x = cls[b * HW + p];
      float pr = 1.f / (1.f + __expf(-x));
      pr = fminf(fmaxf(pr, 1e-4f), 0.9999f);
      if (gt == 1.f) {
        float om = 1.f - pr;
        pos_l = __logf(pr) * om * om;
        npos = 1.f;
      } else {
        float omg = 1.f - gt;
        float w4 = omg * omg;
        w4 *= w4;
        neg_l = __logf(1.f - pr) * pr * pr * w4;
      }
    }

    __shared__ float red[3][4];
    int wid = threadIdx.x >> 6, lane = threadIdx.x & 63;
    float a = waveRedSum(pos_l);
    float c = waveRedSum(neg_l);
    float n = waveRedSum(npos);
    if (lane == 0) { red[0][wid] = a; red[1][wid] = c; red[2][wid] = n; }
    __syncthreads();
    if (threadIdx.x == 0) {
      float pa = 0.f, pc = 0.f, pn = 0.f;
      for (int k = 0; k < 4; ++k) { pa += red[0][k]; pc += red[1][k]; pn += red[2][k]; }
      F[OF_FP + blk * 3 + 0] = pa;
      F[OF_FP + blk * 3 + 1] = pc;
      F[OF_FP + blk * 3 + 2] = pn;
    }
  } else {
    /* ---------- grouped id-loss: one block per (obj i, batch-half) ----------
       4 objects (same i, batches bh*4..bh*4+3) share one W_id pass. */
    int g = blockIdx.x - NFOCAL;
    int i = g >> 1;
    int bh = g & 1;
    int t = threadIdx.x;
    int wid = t >> 6, lane = t & 63;

    __shared__ int   s_ind[4], s_idv[4];
    __shared__ float s_v[4];
    __shared__ float sE[EMB][4];           /* scaled embeddings [dim][obj] */
    __shared__ float slog[NID][4];         /* logits [row][obj] */
    __shared__ float redn[4][4], redm[4][4], reds[4][4];

    /* wave w prepares batch bh*4+w via lane-parallel pid match */
    {
      int b = bh * 4 + wid;
      const float* a1 = ann1 + (b * NOBJ + i) * 8;
      float w = a1[2] * (float)OUT_W;
      float h = a1[3] * (float)OUT_H;
      float cx = fminf(fmaxf(a1[0] * (float)OUT_W, 0.f), (float)(OUT_W - 1));
      float cy = fminf(fmaxf(a1[1] * (float)OUT_H, 0.f), (float)(OUT_H - 1));
      int ctx = (int)cx, cty = (int)cy;
      float pid = a1[5];
      const float* A2 = ann2 + b * NOBJ * 8;
      bool mt = (A2[lane * 8 + 5] == pid);
      unsigned long long bal = __ballot(mt);
      bool has = (bal != 0ull);
      int jm = has ? (__ffsll((unsigned long long)bal) - 1) : 0;
      float w2 = A2[jm * 8 + 2] * (float)OUT_W;
      float h2 = A2[jm * 8 + 3] * (float)OUT_H;
      bool valid = has && (h > 0.f) && (w > 0.f) && (h2 > 0.f) && (w2 > 0.f);
      if (lane == 0) {
        s_ind[wid] = valid ? (cty * OUT_W + ctx) : 0;
        s_idv[wid] = valid ? (int)pid : 0;
        s_v[wid]   = valid ? a1[6] : 0.f;
      }
    }
    __syncthreads();

    /* gather embeddings (dim t for each of 4 objects) + norms */
    float f0 = identis[(size_t)(bh * 4 + 0) * EMB * HW + (size_t)t * HW + s_ind[0]];
    float f1 = identis[(size_t)(bh * 4 + 1) * EMB * HW + (size_t)t * HW + s_ind[1]];
    float f2 = identis[(size_t)(bh * 4 + 2) * EMB * HW + (size_t)t * HW + s_ind[2]];
    float f3 = identis[(size_t)(bh * 4 + 3) * EMB * HW + (size_t)t * HW + s_ind[3]];
    {
      float p0 = waveRedSum(f0 * f0);
      float p1 = waveRedSum(f1 * f1);
      float p2 = waveRedSum(f2 * f2);
      float p3 = waveRedSum(f3 * f3);
      if (lane == 0) {
        redn[wid][0] = p0; redn[wid][1] = p1;
        redn[wid][2] = p2; redn[wid][3] = p3;
      }
    }
    __syncthreads();
    const float EMB_SCALE = 1.41421356237309515f * logf(536.0f);
    float sc0 = EMB_SCALE / fmaxf(sqrtf(redn[0][0]+redn[1][0]+redn[2][0]+redn[3][0]), 1e-12f);
    float sc1 = EMB_SCALE / fmaxf(sqrtf(redn[0][1]+redn[1][1]+redn[2][1]+redn[3][1]), 1e-12f);
    float sc2 = EMB_SCALE / fmaxf(sqrtf(redn[0][2]+redn[1][2]+redn[2][2]+redn[3][2]), 1e-12f);
    float sc3 = EMB_SCALE / fmaxf(sqrtf(redn[0][3]+redn[1][3]+redn[2][3]+redn[3][3]), 1e-12f);
    *(float4*)&sE[t][0] = make_float4(f0 * sc0, f1 * sc1, f2 * sc2, f3 * sc3);
    __syncthreads();

    /* GEMV: rows t and t+256 per thread (both < 537); tail rows 512..536 */
    {
      const float* wr0 = W_id + (size_t)t * EMB;
      const float* wr1 = W_id + (size_t)(t + 256) * EMB;
      float A0=0.f,A1=0.f,A2v=0.f,A3=0.f, B0=0.f,B1=0.f,B2=0.f,B3=0.f;
      for (int k = 0; k < EMB; k += 4) {
        float4 wa = *(const float4*)(wr0 + k);
        float4 wb = *(const float4*)(wr1 + k);
        float4 e0 = *(const float4*)&sE[k][0];
        float4 e1 = *(const float4*)&sE[k + 1][0];
        float4 e2 = *(const float4*)&sE[k + 2][0];
        float4 e3 = *(const float4*)&sE[k + 3][0];
        A0 += wa.x*e0.x + wa.y*e1.x + wa.z*e2.x + wa.w*e3.x;
        A1 += wa.x*e0.y + wa.y*e1.y + wa.z*e2.y + wa.w*e3.y;
        A2v+= wa.x*e0.z + wa.y*e1.z + wa.z*e2.z + wa.w*e3.z;
        A3 += wa.x*e0.w + wa.y*e1.w + wa.z*e2.w + wa.w*e3.w;
        B0 += wb.x*e0.x + wb.y*e1.x + wb.z*e2.x + wb.w*e3.x;
        B1 += wb.x*e0.y + wb.y*e1.y + wb.z*e2.y + wb.w*e3.y;
        B2 += wb.x*e0.z + wb.y*e1.z + wb.z*e2.z + wb.w*e3.z;
        B3 += wb.x*e0.w + wb.y*e1.w + wb.z*e2.w + wb.w*e3.w;
      }
      float bb0 = b_id[t], bb1 = b_id[t + 256];
      *(float4*)&slog[t][0]       = make_float4(A0+bb0, A1+bb0, A2v+bb0, A3+bb0);
      *(float4*)&slog[t + 256][0] = make_float4(B0+bb1, B1+bb1, B2+bb1, B3+bb1);
      if (t < NID - 512) {
        int r2 = t + 512;
        const float* wr2 = W_id + (size_t)r2 * EMB;
        float C0=0.f,C1=0.f,C2=0.f,C3=0.f;
        for (int k = 0; k < EMB; k += 4) {
          float4 wc = *(const float4*)(wr2 + k);
          float4 e0 = *(const float4*)&sE[k][0];
          float4 e1 = *(const float4*)&sE[k + 1][0];
          float4 e2 = *(const float4*)&sE[k + 2][0];
          float4 e3 = *(const float4*)&sE[k + 3][0];
          C0 += wc.x*e0.x + wc.y*e1.x + wc.z*e2.x + wc.w*e3.x;
          C1 += wc.x*e0.y + wc.y*e1.y + wc.z*e2.y + wc.w*e3.y;
          C2 += wc.x*e0.z + wc.y*e1.z + wc.z*e2.z + wc.w*e3.z;
          C3 += wc.x*e0.w + wc.y*e1.w + wc.z*e2.w + wc.w*e3.w;
        }
        float bb2 = b_id[r2];
        *(float4*)&slog[r2][0] = make_float4(C0+bb2, C1+bb2, C2+bb2, C3+bb2);
      }
    }
    __syncthreads();

    /* softmax per object: 64 threads per object (j = t&3) */
    int j = t & 3;
    float mx = -1e30f;
    for (int r = (t >> 2); r < NID; r += 64) mx = fmaxf(mx, slog[r][j]);
    for (int off = 32; off >= 4; off >>= 1) mx = fmaxf(mx, __shfl_xor(mx, off, 64));
    if (lane < 4) redm[wid][lane] = mx;
    __syncthreads();
    float mxf = fmaxf(fmaxf(redm[0][j], redm[1][j]), fmaxf(redm[2][j], redm[3][j]));
    float se = 0.f;
    for (int r = (t >> 2); r < NID; r += 64) se += __expf(slog[r][j] - mxf);
    for (int off = 32; off >= 4; off >>= 1) se += __shfl_xor(se, off, 64);
    if (lane < 4) reds[wid][lane] = se;
    __syncthreads();
    if (t < 4) {
      float set = reds[0][t] + reds[1][t] + reds[2][t] + reds[3][t];
      float mxt = fmaxf(fmaxf(redm[0][t], redm[1][t]), fmaxf(redm[2][t], redm[3][t]));
      float lse = mxt + __logf(set);
      float nll = -s_v[t] * (slog[s_idv[t]][t] - lse);
      F[OF_IDNLL + (bh * 4 + t) * 64 + i] = nll;
    }
  }
}

__global__ void __launch_bounds__(512)
final_kernel(const float* __restrict__ reg,
             const float* __restrict__ viss,
             const float* __restrict__ ann1,
             const float* __restrict__ ann2,
             const float* __restrict__ F,
             const float* __restrict__ s_det,
             const float* __restrict__ s_id,
             float* __restrict__ out) {
  int t = threadIdx.x;
  int b = t >> 6;           /* wave index = batch */
  int lane = t & 63;

  PrepOut P = prep_obj(ann1, ann2, b, lane);
  float msum = waveRedSum(P.vm);

  float rsum = 0.f, vsum = 0.f;
  if (P.vm > 0.f) {
    for (int c = 0; c < 8; ++c) {
      float pred = reg[(b * 8 + c) * HW + P.ind];
      float d = fabsf(pred - P.wh[c]);
      rsum += (d < 1.f) ? 0.5f * d * d : d - 0.5f;
    }
    float s = 1.f / (1.f + __expf(-viss[b * HW + P.ind]));
    s = fminf(fmaxf(s, 1e-4f), 0.9999f);
    float d = fabsf(s - P.v);
    vsum += (d < 1.f) ? 0.5f * d * d : d - 0.5f;
  }
  rsum = waveRedSum(rsum);
  vsum = waveRedSum(vsum);

  /* focal partial reduce: 162 blocks per batch, strided by lane */
  float pa = 0.f, pc = 0.f, pn = 0.f;
  for (int e = lane; e < NFBLK; e += 64) {
    const float* fp = F + OF_FP + (b * NFBLK + e) * 3;
    pa += fp[0]; pc += fp[1]; pn += fp[2];
  }
  pa = waveRedSum(pa);
  pc = waveRedSum(pc);
  pn = waveRedSum(pn);

  /* id NLL reduce: 64 objects per batch, one per lane */
  float idv = waveRedSum(F[OF_IDNLL + b * 64 + lane]);

  __shared__ float L[8][4];
  if (lane == 0) {
    L[b][0] = (pn > 0.f) ? (-(pa + pc) / fmaxf(pn, 1.f)) : (-pc);
    L[b][1] = rsum / (msum + 0.0001f);
    L[b][2] = vsum / (msum + 0.0001f);
    L[b][3] = idv / fmaxf(msum, 1.f);
  }
  __syncthreads();
  if (t == 0) {
    float cl = 0.f, rl = 0.f, vl = 0.f, il = 0.f;
    for (int k = 0; k < 8; ++k) {
      cl += L[k][0]; rl += L[k][1]; vl += L[k][2]; il += L[k][3];
    }
    out[0] = cl / 8.f;
    out[1] = rl / 8.f;
    out[2] = vl / 8.f;
    out[3] = il / 8.f;
    out[4] = s_det[0];
    out[5] = s_id[0];
  }
}

extern "C" void kernel_launch(void* const* d_in, const int* in_sizes, int n_in,
                              void* d_out, int out_size, void* d_ws, size_t ws_size,
                              hipStream_t stream) {
  const float* cls     = (const float*)d_in[0];
  const float* reg     = (const float*)d_in[1];
  const float* viss    = (const float*)d_in[2];
  const float* identis = (const float*)d_in[3];
  const float* ann1    = (const float*)d_in[4];
  const float* ann2    = (const float*)d_in[5];
  const float* W_id    = (const float*)d_in[6];
  const float* b_id    = (const float*)d_in[7];
  const float* s_det   = (const float*)d_in[8];
  const float* s_id    = (const float*)d_in[9];
  float* F = (float*)d_ws;

  main_kernel<<<NFOCAL + NIDG, 256, 0, stream>>>(cls, identis, W_id, b_id,
                                                 ann1, ann2, F);
  final_kernel<<<1, 512, 0, stream>>>(reg, viss, ann1, ann2, F,
                                      s_det, s_id, (float*)d_out);
}